// Round 4
// baseline (90.225 us; speedup 1.0000x reference)
//
#include <hip/hip_runtime.h>

typedef __bf16 bf16x8 __attribute__((ext_vector_type(8)));
typedef float  f32x4  __attribute__((ext_vector_type(4)));

constexpr int HID = 64;
constexpr float K1   = 27.178297f;        // sqrt(512 * log2(e)); enc = exp2(-(K1*(x-c))^2)
constexpr float STEP = -K1 / 31.0f;       // centers[i] = i/31

// MFMA 16x16x32 bf16 layouts (verified m89/m91):
//   A-frag: lane l holds A[m=l&15][k=(l>>4)*8+j]
//   B-frag: lane l holds B[k=(l>>4)*8+j][n=l&15]
//   C/D  : lane l reg i holds D[m=(l>>4)*4+i][n=l&15]
// Transposed compute: D[c][row] = W^T @ enc^T. k-permutation
// pi(32kk2+8g+j) = 32kk2+16(j>>2)+4g+(j&3) on W2/W3 rows makes each layer's
// B-frag equal to the previous layer's accumulators repacked in-lane.

// ws layout (bf16x8 units): frag f in [0,28): W1 [kk*4+mt];
// f in [28,36): W2 [mt*2+kk2]; f in [36,44): W3 [mt*2+kk2]. 64 lanes each.
__global__ void prep_kernel(const float* __restrict__ W1,
                            const float* __restrict__ W2,
                            const float* __restrict__ W3,
                            bf16x8* __restrict__ ws)
{
    const int f = blockIdx.x;
    const int l = threadIdx.x;
    const int g = l >> 4, r = l & 15;
    bf16x8 v;
    if (f < 28) {
        const int kk = f >> 2, mt = f & 3;
#pragma unroll
        for (int j = 0; j < 8; ++j)
            v[j] = (__bf16)W1[(32 * kk + 8 * g + j) * HID + 16 * mt + r];
    } else {
        const float* W = (f < 36) ? W2 : W3;
        const int fi = (f < 36) ? (f - 28) : (f - 36);
        const int mt = fi >> 1, kk2 = fi & 1;
#pragma unroll
        for (int j = 0; j < 8; ++j) {
            const int k = 32 * kk2 + 16 * (j >> 2) + 4 * g + (j & 3);
            v[j] = (__bf16)W[k * HID + 16 * mt + r];
        }
    }
    ws[f * 64 + l] = v;
}

__device__ __forceinline__ void load_x(const float* __restrict__ pos,
                                       const float* __restrict__ wi,
                                       const float* __restrict__ rough,
                                       int row, float* x)
{
    x[0] = pos[row * 3 + 0]; x[1] = pos[row * 3 + 1]; x[2] = pos[row * 3 + 2];
    x[3] = wi[row * 3 + 0];  x[4] = wi[row * 3 + 1];  x[5] = wi[row * 3 + 2];
    x[6] = rough[row];
}

// One pass per block: 4 waves x 64 rows (4 row-tiles of 16) = 256 rows.
__global__ __launch_bounds__(256, 3)
void cond_net_kernel(const float* __restrict__ pos, const float* __restrict__ wi,
                     const float* __restrict__ rough,
                     const float* __restrict__ b1, const float* __restrict__ b2,
                     const float* __restrict__ b3,
                     const bf16x8* __restrict__ ws,
                     float* __restrict__ out)
{
    __shared__ __align__(16) char lds[44 * 1024 + 768];   // 44 frag-KiB + 3x256B bias

    const int tid = threadIdx.x;
    const int l = tid & 63, wv = tid >> 6, g = l >> 4, r = l & 15;

    // stage all 44 weight fragments (1 KiB each), 11 per wave, lane-linear dest
#pragma unroll
    for (int i = 0; i < 11; ++i) {
        const int fr = wv * 11 + i;
        __builtin_amdgcn_global_load_lds(
            (const __attribute__((address_space(1))) void*)(ws + fr * 64 + l),
            (__attribute__((address_space(3))) void*)(lds + fr * 1024),
            16, 0, 0);
    }
    // stage biases (64 f32 each) at 44 KiB, one wave each
    if (wv < 3) {
        const float* bp = (wv == 0) ? b1 : (wv == 1) ? b2 : b3;
        __builtin_amdgcn_global_load_lds(
            (const __attribute__((address_space(1))) void*)(bp + l),
            (__attribute__((address_space(3))) void*)(lds + 44 * 1024 + wv * 256),
            4, 0, 0);
    }

    // input rows: tile t covers rows rbase + t*16 + r
    const int rbase = blockIdx.x * 256 + wv * 64 + r;
    float A[4][7];
#pragma unroll
    for (int t = 0; t < 4; ++t) {
        float x[7];
        load_x(pos, wi, rough, rbase + 16 * t, x);
#pragma unroll
        for (int d = 0; d < 7; ++d)
            A[t][d] = fmaf(K1, fminf(fmaxf(x[d], 0.0f), 1.0f), STEP * (float)(8 * g));
    }

    __syncthreads();   // drains global_load_lds + barrier

    const char* lb = (const char*)lds + l * 16;
    const char* bb = (const char*)lds + 44 * 1024 + g * 16;

    // ---- layer 1: all 4 tiles share each W1 fragment read ----
    f32x4 acc1[4][4];
    {
        f32x4 b1v[4];
#pragma unroll
        for (int mt = 0; mt < 4; ++mt) b1v[mt] = *(const f32x4*)(bb + mt * 64);
#pragma unroll
        for (int t = 0; t < 4; ++t)
#pragma unroll
            for (int mt = 0; mt < 4; ++mt) acc1[t][mt] = b1v[mt];
    }

#pragma unroll
    for (int kk = 0; kk < 7; ++kk) {
        bf16x8 e[4];
#pragma unroll
        for (int t = 0; t < 4; ++t)
#pragma unroll
            for (int j = 0; j < 8; ++j) {
                const float d = A[t][kk] + (float)j * STEP;
                e[t][j] = (__bf16)__builtin_amdgcn_exp2f(-(d * d));
            }
#pragma unroll
        for (int mt = 0; mt < 4; ++mt) {
            const bf16x8 wf = *(const bf16x8*)(lb + (kk * 4 + mt) * 1024);
#pragma unroll
            for (int t = 0; t < 4; ++t)
                acc1[t][mt] = __builtin_amdgcn_mfma_f32_16x16x32_bf16(wf, e[t], acc1[t][mt], 0, 0, 0);
        }
    }

    // ---- layers 2+3 in tile-pairs sharing W2/W3 fragment reads ----
#pragma unroll
    for (int p = 0; p < 2; ++p) {
        bf16x8 h1f[2][2];
#pragma unroll
        for (int tt = 0; tt < 2; ++tt)
#pragma unroll
            for (int kk2 = 0; kk2 < 2; ++kk2) {
                bf16x8 v;
#pragma unroll
                for (int j = 0; j < 8; ++j)
                    v[j] = (__bf16)fmaxf(acc1[2 * p + tt][2 * kk2 + (j >> 2)][j & 3], 0.0f);
                h1f[tt][kk2] = v;
            }

        f32x4 acc2[2][4];
#pragma unroll
        for (int mt = 0; mt < 4; ++mt) {
            const f32x4 b2v = *(const f32x4*)(bb + 256 + mt * 64);
            acc2[0][mt] = b2v; acc2[1][mt] = b2v;
        }
#pragma unroll
        for (int kk2 = 0; kk2 < 2; ++kk2)
#pragma unroll
            for (int mt = 0; mt < 4; ++mt) {
                const bf16x8 wf = *(const bf16x8*)(lb + (28 + mt * 2 + kk2) * 1024);
#pragma unroll
                for (int tt = 0; tt < 2; ++tt)
                    acc2[tt][mt] = __builtin_amdgcn_mfma_f32_16x16x32_bf16(wf, h1f[tt][kk2], acc2[tt][mt], 0, 0, 0);
            }

        bf16x8 h2f[2][2];
#pragma unroll
        for (int tt = 0; tt < 2; ++tt)
#pragma unroll
            for (int kk2 = 0; kk2 < 2; ++kk2) {
                bf16x8 v;
#pragma unroll
                for (int j = 0; j < 8; ++j)
                    v[j] = (__bf16)fmaxf(acc2[tt][2 * kk2 + (j >> 2)][j & 3], 0.0f);
                h2f[tt][kk2] = v;
            }

        f32x4 acc3[2][4];
#pragma unroll
        for (int mt = 0; mt < 4; ++mt) {
            const f32x4 b3v = *(const f32x4*)(bb + 512 + mt * 64);
            acc3[0][mt] = b3v; acc3[1][mt] = b3v;
        }
#pragma unroll
        for (int kk2 = 0; kk2 < 2; ++kk2)
#pragma unroll
            for (int mt = 0; mt < 4; ++mt) {
                const bf16x8 wf = *(const bf16x8*)(lb + (36 + mt * 2 + kk2) * 1024);
#pragma unroll
                for (int tt = 0; tt < 2; ++tt)
                    acc3[tt][mt] = __builtin_amdgcn_mfma_f32_16x16x32_bf16(wf, h2f[tt][kk2], acc3[tt][mt], 0, 0, 0);
            }

#pragma unroll
        for (int tt = 0; tt < 2; ++tt) {
            const int row = rbase + 16 * (2 * p + tt);
#pragma unroll
            for (int mt = 0; mt < 4; ++mt)
                __builtin_nontemporal_store(acc3[tt][mt],
                    (f32x4*)(out + (size_t)row * 64 + 16 * mt + 4 * g));
        }
    }
}

extern "C" void kernel_launch(void* const* d_in, const int* in_sizes, int n_in,
                              void* d_out, int out_size, void* d_ws, size_t ws_size,
                              hipStream_t stream) {
    const float* pos     = (const float*)d_in[0];
    const float* wi      = (const float*)d_in[1];
    const float* rough   = (const float*)d_in[2];
    const float* W1      = (const float*)d_in[3];
    const float* b1      = (const float*)d_in[4];
    const float* W2      = (const float*)d_in[5];
    const float* b2      = (const float*)d_in[6];
    const float* W3      = (const float*)d_in[7];
    const float* b3      = (const float*)d_in[8];
    float* out = (float*)d_out;

    bf16x8* ws = (bf16x8*)d_ws;

    const int n = in_sizes[0] / 3;          // 1048576 rows
    hipLaunchKernelGGL(prep_kernel, dim3(44), dim3(64), 0, stream, W1, W2, W3, ws);
    hipLaunchKernelGGL(cond_net_kernel, dim3(n / 256), dim3(256), 0, stream,
                       pos, wi, rough, b1, b2, b3, (const bf16x8*)ws, out);
}